// Round 2
// baseline (123.599 us; speedup 1.0000x reference)
//
#include <hip/hip_runtime.h>
#include <math.h>

// Third-order scattering, restructured via Parseval (matching the reference's
// actual broadcasting):
//   out[b,i,j] = (1/MN^2) * sum_k Fp_j[k]^2 * Re( XA_{b,i}[k] * conj(X_b[k]) )
// where X = fft2(x), XA_i = fft2(abs_eps(ifft2(F_i * X))), all in a consistent
// bit-reversed (per-axis) frequency layout; filters permuted once to match.
//
// FFT: 128-pt per 64-lane wave, registers + shfl_xor, DIF fwd (natural->sigma),
// mirrored inverse (sigma->natural, unnormalized x128/axis; 1/16384 folded into abs).

#define PI_F 3.14159265358979323846f

__device__ __forceinline__ void make_tw(int lane, float* twr, float* twi) {
#pragma unroll
  for (int s = 0; s < 6; ++s) {
    int h = 32 >> s;
    float ang = -PI_F * (float)(lane & (h - 1)) / (float)h;  // W_{2h}^{j}
    float sv, cv;
    sincosf(ang, &sv, &cv);
    twr[s] = cv; twi[s] = sv;
  }
  float ang = -PI_F * (float)lane / 64.0f;  // W_128^t
  float sv, cv;
  sincosf(ang, &sv, &cv);
  twr[6] = cv; twi[6] = sv;
}

// Forward DIF: input lane t holds a=x[t], b=x[t+64] (natural order).
// Output: slot s holds X[brev7(s)]; slot t -> a, slot t+64 -> b.
__device__ __forceinline__ void fft128_fwd(float& ar, float& ai, float& br, float& bi,
                                           const float* twr, const float* twi, int lane) {
  // span-64 stage (in-thread)
  float ur = ar + br, ui = ai + bi;
  float vr = ar - br, vi = ai - bi;
  ar = ur; ai = ui;
  br = vr * twr[6] - vi * twi[6];
  bi = vr * twi[6] + vi * twr[6];
#pragma unroll
  for (int s = 0; s < 6; ++s) {
    int h = 32 >> s;  // 32,16,8,4,2,1
    float wr = twr[s], wi = twi[s];
    bool hi = (lane & h) != 0;
    float pr, pi2;
    pr = __shfl_xor(ar, h, 64); pi2 = __shfl_xor(ai, h, 64);
    if (!hi) { ar += pr; ai += pi2; }
    else { float dr = pr - ar, di = pi2 - ai; ar = dr * wr - di * wi; ai = dr * wi + di * wr; }
    pr = __shfl_xor(br, h, 64); pi2 = __shfl_xor(bi, h, 64);
    if (!hi) { br += pr; bi += pi2; }
    else { float dr = pr - br, di = pi2 - bi; br = dr * wr - di * wi; bi = dr * wi + di * wr; }
  }
}

// Inverse (exact mirror of fwd, conjugate twiddles, no /2 => output = 128 * ifft1d).
// Input: slot layout of fft128_fwd output. Output: natural order (a=y[t], b=y[t+64]).
__device__ __forceinline__ void fft128_inv(float& ar, float& ai, float& br, float& bi,
                                           const float* twr, const float* twi, int lane) {
#pragma unroll
  for (int s = 5; s >= 0; --s) {
    int h = 32 >> s;  // 1,2,4,8,16,32
    float wr = twr[s], wi = -twi[s];
    bool hi = (lane & h) != 0;
    float pr, pi2;
    pr = __shfl_xor(ar, h, 64); pi2 = __shfl_xor(ai, h, 64);
    if (!hi) { ar += pr * wr - pi2 * wi; ai += pr * wi + pi2 * wr; }
    else { float tr = ar * wr - ai * wi, ti = ar * wi + ai * wr; ar = pr - tr; ai = pi2 - ti; }
    pr = __shfl_xor(br, h, 64); pi2 = __shfl_xor(bi, h, 64);
    if (!hi) { br += pr * wr - pi2 * wi; bi += pr * wi + pi2 * wr; }
    else { float tr = br * wr - bi * wi, ti = br * wi + bi * wr; br = pr - tr; bi = pi2 - ti; }
  }
  // undo span-64
  float wr = twr[6], wi = -twi[6];
  float tr = br * wr - bi * wi, ti = br * wi + bi * wr;
  float nr = ar + tr, ni = ai + ti;
  br = ar - tr; bi = ai - ti;
  ar = nr; ai = ni;
}

// ---- kernels ----

// Fp[c][su][sv] = F[c][brev7(su)][brev7(sv)]
__global__ void k_permute(const float* __restrict__ F, float* __restrict__ Fp) {
  int idx = blockIdx.x * 256 + threadIdx.x;  // 33*16384 exact
  int c = idx >> 14;
  int su = (idx >> 7) & 127, sv = idx & 127;
  int u = __brev((unsigned)su) >> 25, v = __brev((unsigned)sv) >> 25;
  Fp[idx] = F[(c << 14) + (u << 7) + v];
}

// forward FFT along rows (v axis) of x, real input. grid: 2 imgs * 128 rows waves.
__global__ void k_fwd_rows_x(const float* __restrict__ x, float2* __restrict__ Sx) {
  int wid = (blockIdx.x * 256 + threadIdx.x) >> 6;
  int lane = threadIdx.x & 63;
  int img = wid >> 7, r = wid & 127;
  float twr[7], twi[7]; make_tw(lane, twr, twi);
  const float* row = x + img * 16384 + r * 128;
  float ar = row[lane], ai = 0.f, br = row[lane + 64], bi = 0.f;
  fft128_fwd(ar, ai, br, bi, twr, twi, lane);
  float2* o = Sx + img * 16384 + r * 128;
  o[lane] = make_float2(ar, ai);
  o[lane + 64] = make_float2(br, bi);
}

// forward FFT along cols (u axis). output X in (sigma_u, sigma_v) layout.
__global__ void k_fwd_cols_x(const float2* __restrict__ Sx, float2* __restrict__ X) {
  int wid = (blockIdx.x * 256 + threadIdx.x) >> 6;
  int lane = threadIdx.x & 63;
  int img = wid >> 7, c = wid & 127;
  float twr[7], twi[7]; make_tw(lane, twr, twi);
  const float2* base = Sx + img * 16384;
  float2 va = base[lane * 128 + c], vb = base[(lane + 64) * 128 + c];
  float ar = va.x, ai = va.y, br = vb.x, bi = vb.y;
  fft128_fwd(ar, ai, br, bi, twr, twi, lane);
  float2* o = X + img * 16384;
  o[lane * 128 + c] = make_float2(ar, ai);
  o[(lane + 64) * 128 + c] = make_float2(br, bi);
}

// per (b,i): Y = Fp_i * X[b] (sigma layout), inverse FFT along v. 66*128 waves.
__global__ void k_inv_rows(const float2* __restrict__ X, const float* __restrict__ Fp,
                           float2* __restrict__ S) {
  int wid = (blockIdx.x * 256 + threadIdx.x) >> 6;
  int lane = threadIdx.x & 63;
  int im = wid >> 7, r = wid & 127;  // im = b*33+i
  int b = im / 33, i = im - b * 33;
  float twr[7], twi[7]; make_tw(lane, twr, twi);
  const float2* Xr = X + b * 16384 + r * 128;
  const float* Fr = Fp + i * 16384 + r * 128;
  float2 x0 = Xr[lane]; float f0 = Fr[lane];
  float2 x1 = Xr[lane + 64]; float f1 = Fr[lane + 64];
  float ar = x0.x * f0, ai = x0.y * f0, br = x1.x * f1, bi = x1.y * f1;
  fft128_inv(ar, ai, br, bi, twr, twi, lane);
  float2* o = S + im * 16384 + r * 128;  // (sigma_u, natural v)
  o[lane] = make_float2(ar, ai);
  o[lane + 64] = make_float2(br, bi);
}

// inverse FFT along u + abs_eps (with 1/16384 norm). out xaT[im][c][u] (transposed).
__global__ void k_inv_cols_abs(const float2* __restrict__ S, float* __restrict__ xaT) {
  int wid = (blockIdx.x * 256 + threadIdx.x) >> 6;
  int lane = threadIdx.x & 63;
  int im = wid >> 7, c = wid & 127;
  float twr[7], twi[7]; make_tw(lane, twr, twi);
  const float2* base = S + im * 16384;
  float2 va = base[lane * 128 + c], vb = base[(lane + 64) * 128 + c];
  float ar = va.x, ai = va.y, br = vb.x, bi = vb.y;
  fft128_inv(ar, ai, br, bi, twr, twi, lane);
  const float sc = 1.0f / 16384.0f;
  float t0r = ar * sc, t0i = ai * sc;
  float t1r = br * sc, t1i = bi * sc;
  float* o = xaT + im * 16384 + c * 128;
  o[lane] = sqrtf(t0r * t0r + t0i * t0i + 1e-6f);
  o[lane + 64] = sqrtf(t1r * t1r + t1i * t1i + 1e-6f);
}

// forward FFT along u (contiguous axis of xaT). out S2[im][c][sigma_u].
__global__ void k_fwd_rows_xa(const float* __restrict__ xaT, float2* __restrict__ S2) {
  int wid = (blockIdx.x * 256 + threadIdx.x) >> 6;
  int lane = threadIdx.x & 63;
  int im = wid >> 7, c = wid & 127;
  float twr[7], twi[7]; make_tw(lane, twr, twi);
  const float* row = xaT + im * 16384 + c * 128;
  float ar = row[lane], ai = 0.f, br = row[lane + 64], bi = 0.f;
  fft128_fwd(ar, ai, br, bi, twr, twi, lane);
  float2* o = S2 + im * 16384 + c * 128;
  o[lane] = make_float2(ar, ai);
  o[lane + 64] = make_float2(br, bi);
}

// forward FFT along v; fuse g = Re(XA * conj(X)). wave per (im, q=sigma_u).
__global__ void k_fwd_cols_g(const float2* __restrict__ S2, const float2* __restrict__ X,
                             float* __restrict__ g) {
  int wid = (blockIdx.x * 256 + threadIdx.x) >> 6;
  int lane = threadIdx.x & 63;
  int im = wid >> 7, q = wid & 127;
  int b = im / 33;
  float twr[7], twi[7]; make_tw(lane, twr, twi);
  const float2* base = S2 + im * 16384;
  float2 va = base[lane * 128 + q], vb = base[(lane + 64) * 128 + q];
  float ar = va.x, ai = va.y, br = vb.x, bi = vb.y;
  fft128_fwd(ar, ai, br, bi, twr, twi, lane);
  int k0 = q * 128 + lane, k1 = k0 + 64;
  float2 X0 = X[b * 16384 + k0], X1 = X[b * 16384 + k1];
  g[im * 16384 + k0] = ar * X0.x + ai * X0.y;
  g[im * 16384 + k1] = br * X1.x + bi * X1.y;
}

// out[b*672+t] = (1/16384^2) * sum_k g[b,i(t),k] * Fp[j(t),k]^2
__global__ void k_reduce(const float* __restrict__ g, const float* __restrict__ Fp,
                         float* __restrict__ out) {
  int o = blockIdx.x;  // 0..1343
  int b = o / 672, t = o - b * 672;
  int rem = t, j1 = 0;
  for (;;) {
    int c = 8 * ((4 - j1) * 8 + 1);
    if (rem < c) break;
    rem -= c; ++j1;
  }
  int per = (4 - j1) * 8 + 1;
  int l1 = rem / per, rr = rem - l1 * per;
  int i = j1 * 8 + l1;
  int j = (rr == per - 1) ? 32 : (j1 * 8 + rr);
  const float* gr = g + (b * 33 + i) * 16384;
  const float* fr = Fp + j * 16384;
  float s = 0.f;
  for (int k = threadIdx.x; k < 16384; k += 256) {
    float f = fr[k];
    s += gr[k] * f * f;
  }
#pragma unroll
  for (int off = 32; off > 0; off >>= 1) s += __shfl_down(s, off, 64);
  __shared__ float red[4];
  int w = threadIdx.x >> 6;
  if ((threadIdx.x & 63) == 0) red[w] = s;
  __syncthreads();
  if (threadIdx.x == 0) {
    float tot = (red[0] + red[1]) + (red[2] + red[3]);
    out[o] = tot * (1.0f / 16384.0f) * (1.0f / 16384.0f);
  }
}

extern "C" void kernel_launch(void* const* d_in, const int* in_sizes, int n_in,
                              void* d_out, int out_size, void* d_ws, size_t ws_size,
                              hipStream_t stream) {
  (void)in_sizes; (void)n_in; (void)out_size; (void)ws_size;
  const float* x = (const float*)d_in[0];   // (2,1,128,128)
  const float* F = (const float*)d_in[1];   // (1,33,128,128)
  float* out = (float*)d_out;               // (2,672)
  char* ws = (char*)d_ws;
  // ws layout (bytes):
  //   X  @ 0        : 2*16384 float2   (262144)
  //   Fp @ 262144   : 33*16384 float   (2162688)
  //   S  @ 2424832  : 66*16384 float2  (8650752)  (also S2; slots 0,1 reused for x scratch)
  //   T  @ 11075584 : 66*16384 float   (4325376)  (xaT, then reused as g)
  // total 15400960 bytes
  float2* X = (float2*)(ws + 0);
  float* Fp = (float*)(ws + 262144);
  float2* S = (float2*)(ws + 2424832);
  float* T = (float*)(ws + 11075584);

  hipLaunchKernelGGL(k_permute, dim3(2112), dim3(256), 0, stream, F, Fp);
  hipLaunchKernelGGL(k_fwd_rows_x, dim3(64), dim3(256), 0, stream, x, S);
  hipLaunchKernelGGL(k_fwd_cols_x, dim3(64), dim3(256), 0, stream, S, X);
  hipLaunchKernelGGL(k_inv_rows, dim3(2112), dim3(256), 0, stream, X, Fp, S);
  hipLaunchKernelGGL(k_inv_cols_abs, dim3(2112), dim3(256), 0, stream, S, T);
  hipLaunchKernelGGL(k_fwd_rows_xa, dim3(2112), dim3(256), 0, stream, T, S);
  hipLaunchKernelGGL(k_fwd_cols_g, dim3(2112), dim3(256), 0, stream, S, X, T);
  hipLaunchKernelGGL(k_reduce, dim3(1344), dim3(256), 0, stream, T, Fp, out);
}